// Round 8
// baseline (302.202 us; speedup 1.0000x reference)
//
#include <hip/hip_runtime.h>
#include <stdint.h>

// ---------------------------------------------------------------------------
// MHA: B=4 S=2048 H=16 Dk=Dv=64 HIDDEN=1024, fp32 in/out, bf16 MFMA compute.
// Pipeline: detect -> mask_bits -> pack_w -> (cvt_x(z) -> gemm_qkv(z)) x3
//           -> transpose_v -> attn -> gemm_out
// This round: attention on 32x32x16 MFMAs. Swapped QK^T gives S^T with
// q=lane&31 (one q per lane); P^T becomes the PV B-operand via 2x
// v_permlane32_swap per kv-step (lane+-32 half exchange); l via in-lane
// tree sum + shfl_xor(32). 16 MFMA/tile (was 56), 16 ds_read_b128 (was 24).
// Scratch (72 MiB + 4B):
//   [0,16MiB)   XbZ (bf16 X for current z) ... later reused as Ob (attn out)
//   [16,24MiB)  Wt  (packed bf16 weights, 4x 1024x1024, N-major)
//   [24,72MiB)  QKV (bf16, [z][B][H][S][64])
//   @72MiB      mask-dtype flag (4B)
// d_out overlay: [0,2MiB) mask bitmask, [2,18MiB) VT. gemm_out overwrites last.
// ---------------------------------------------------------------------------

typedef __bf16 bf16x8_t __attribute__((ext_vector_type(8)));
typedef float f32x4_t __attribute__((ext_vector_type(4)));
typedef float f32x16_t __attribute__((ext_vector_type(16)));

#define HID   1024
#define SLEN  2048
#define BATCH 4
#define NH    16
#define MROWS 8192   // BATCH*SLEN
#define L2E   1.44269504f

__device__ __forceinline__ unsigned short bfbits(float f) {
  union { __bf16 h; unsigned short u; } v; v.h = (__bf16)f; return v.u;
}
__device__ __forceinline__ unsigned int packbf(float a, float b) {
  return (unsigned int)bfbits(a) | ((unsigned int)bfbits(b) << 16);
}
__device__ __forceinline__ float fast_exp2(float x) {
#if __has_builtin(__builtin_amdgcn_exp2f)
  return __builtin_amdgcn_exp2f(x);
#else
  return __exp2f(x);
#endif
}

__device__ __forceinline__ void gload_lds16(const void* g, void* l) {
  __builtin_amdgcn_global_load_lds((const __attribute__((address_space(1))) void*)g,
                                   (__attribute__((address_space(3))) void*)l,
                                   16, 0, 0);
}

// LDS tiles are [rows][64] bf16 (128B rows, 8 slots of 16B), XOR-swizzled:
// physical slot = logical slot ^ (row & 7).
__device__ __forceinline__ bf16x8_t frag_ld(const unsigned short* lds, int row, int sblk) {
  int sp = sblk ^ (row & 7);
  return *(const bf16x8_t*)(lds + (row << 6) + (sp << 3));
}

// ---- mask dtype detector: bool bytes (1B) vs int32 --------------------------
__global__ void detect_mask_kernel(const unsigned int* __restrict__ m,
                                   unsigned int* __restrict__ flag) {
  unsigned int v = m[threadIdx.x];
  unsigned long long b = __ballot(v > 1u);         // packed bools give words > 1
  if (threadIdx.x == 0) flag[0] = 0u;
  __syncthreads();
  if ((threadIdx.x & 63) == 0 && b) atomicOr(flag, 1u);  // 1 => byte mask
}

// ---- mask -> bitmask: bits[(b*S+q)*32 + kw] bit i = mask[b][q][kw*64+i] -----
__global__ __launch_bounds__(256) void mask_bits_kernel(const void* __restrict__ maskp,
    const unsigned int* __restrict__ flag, unsigned long long* __restrict__ bits) {
  int lane = threadIdx.x & 63, wv = threadIdx.x >> 6;
  bool bytemask = flag[0] != 0u;
  size_t w0 = (size_t)blockIdx.x * 64 + (size_t)wv * 16;
  for (int it = 0; it < 16; ++it) {
    size_t word = w0 + it;
    unsigned int v;
    if (bytemask) v = ((const unsigned char*)maskp)[word * 64 + lane];
    else          v = ((const unsigned int*)maskp)[word * 64 + lane];
    unsigned long long bm = __ballot(v != 0u);
    if (lane == 0) bits[word] = bm;
  }
}

// ---- fp32 -> bf16 conversion of one hidden input ----------------------------
__global__ __launch_bounds__(256) void cvt_x_kernel(const float* __restrict__ src,
                                                    unsigned short* __restrict__ xb) {
  size_t base = (size_t)blockIdx.x * 1024 + (size_t)threadIdx.x * 4;
  float4 v = *(const float4*)(src + base);
  ushort4 o;
  o.x = bfbits(v.x); o.y = bfbits(v.y); o.z = bfbits(v.z); o.w = bfbits(v.w);
  *(ushort4*)(xb + base) = o;
}

// ---- pack weights into bf16, N-major: Wt[z][n][k] ---------------------------
__global__ __launch_bounds__(256) void pack_w_kernel(const float* __restrict__ wq,
    const float* __restrict__ wk, const float* __restrict__ wv,
    const float* __restrict__ wo, unsigned short* __restrict__ wt) {
  int z = blockIdx.y;
  int id = blockIdx.x * 256 + threadIdx.x;
  int n = id >> 8;
  int d0 = (id & 255) << 2;
  ushort4 o;
  if (z < 3) {
    const float* w = z == 0 ? wq : (z == 1 ? wk : wv);
    const float* base = w + (size_t)(n >> 6) * (HID * 64) + (n & 63);
    o.x = bfbits(base[(size_t)(d0 + 0) * 64]);
    o.y = bfbits(base[(size_t)(d0 + 1) * 64]);
    o.z = bfbits(base[(size_t)(d0 + 2) * 64]);
    o.w = bfbits(base[(size_t)(d0 + 3) * 64]);
  } else {
    o.x = bfbits(wo[(size_t)(d0 + 0) * HID + n]);
    o.y = bfbits(wo[(size_t)(d0 + 1) * HID + n]);
    o.z = bfbits(wo[(size_t)(d0 + 2) * HID + n]);
    o.w = bfbits(wo[(size_t)(d0 + 3) * HID + n]);
  }
  *(ushort4*)(wt + (size_t)z * (HID * HID) + (size_t)n * HID + d0) = o;
}

// ---- V -> VT[bh][dv][s] transpose (64x64 tiles via swizzled LDS) ------------
__global__ __launch_bounds__(256) void transpose_v_kernel(
    const unsigned short* __restrict__ V, unsigned short* __restrict__ VT) {
  __shared__ unsigned int t[64 * 32];  // [d][8 slots of 4 u32], slot ^= (d&7)
  int tid = threadIdx.x;
  int bh = blockIdx.y;
  int s0 = blockIdx.x * 64;
  const unsigned short* Vb = V + (size_t)bh * (SLEN * 64);
  int sp = tid >> 3, d0 = (tid & 7) << 3;        // s-pair 0..31, d block
  const unsigned short* vs = Vb + (size_t)(s0 + sp * 2) * 64 + d0;
  bf16x8_t v0 = *(const bf16x8_t*)(vs);
  bf16x8_t v1 = *(const bf16x8_t*)(vs + 64);
  union { __bf16 b[8]; unsigned short u[8]; } a0, a1;
  *(bf16x8_t*)a0.b = v0; *(bf16x8_t*)a1.b = v1;
#pragma unroll
  for (int e = 0; e < 8; ++e) {
    int d = d0 + e;
    unsigned int val = (unsigned int)a0.u[e] | ((unsigned int)a1.u[e] << 16);
    int slot = (sp >> 2) ^ (d & 7);
    t[d * 32 + slot * 4 + (sp & 3)] = val;
  }
  __syncthreads();
#pragma unroll
  for (int it = 0; it < 2; ++it) {
    int gid = it * 256 + tid;
    int d = gid >> 3, slot = gid & 7;
    uint4 vv = *(const uint4*)(t + d * 32 + ((slot ^ (d & 7)) << 2));
    *(uint4*)(VT + (size_t)bh * (64 * SLEN) + (size_t)d * SLEN + s0 + slot * 8) = vv;
  }
}

// ---- 128x128xK=1024 GEMM mainloop, 2-phase pipelined (BK=64, dbuf LDS) ------
__device__ __forceinline__ void gemm_stage(const unsigned short* __restrict__ A,
    const unsigned short* __restrict__ B, unsigned short* la, unsigned short* lb,
    int tid, int w, int kt) {
#pragma unroll
  for (int i = 0; i < 4; ++i) {
    int flat = i * 256 + tid;
    int row = flat >> 3;
    int sl = (flat & 7) ^ (row & 7);
    gload_lds16(A + (size_t)row * HID + kt + sl * 8, la + ((i * 256 + w * 64) << 3));
    gload_lds16(B + (size_t)row * HID + kt + sl * 8, lb + ((i * 256 + w * 64) << 3));
  }
}

__device__ __forceinline__ void gemm_tile_mainloop(const unsigned short* __restrict__ A,
    const unsigned short* __restrict__ B, unsigned short (*lA)[128 * 64],
    unsigned short (*lB)[128 * 64], int tid, f32x4_t (&acc)[4][4]) {
  int lane = tid & 63, w = tid >> 6;
  int wr = (w >> 1) << 6, wc = (w & 1) << 6;
  gemm_stage(A, B, lA[0], lB[0], tid, w, 0);
  __syncthreads();
  int cur = 0;
  for (int kt = 0; kt < HID; kt += 64) {
    if (kt + 64 < HID)
      gemm_stage(A, B, lA[cur ^ 1], lB[cur ^ 1], tid, w, kt + 64);
    const unsigned short* la = lA[cur];
    const unsigned short* lb = lB[cur];
#pragma unroll
    for (int kk = 0; kk < 2; ++kk) {
      bf16x8_t af[4], bfr[4];
#pragma unroll
      for (int mi = 0; mi < 4; ++mi)
        af[mi] = frag_ld(la, wr + mi * 16 + (lane & 15), kk * 4 + (lane >> 4));
#pragma unroll
      for (int ni = 0; ni < 4; ++ni)
        bfr[ni] = frag_ld(lb, wc + ni * 16 + (lane & 15), kk * 4 + (lane >> 4));
#pragma unroll
      for (int mi = 0; mi < 4; ++mi)
#pragma unroll
        for (int ni = 0; ni < 4; ++ni)
          acc[mi][ni] = __builtin_amdgcn_mfma_f32_16x16x32_bf16(af[mi], bfr[ni],
                                                                acc[mi][ni], 0, 0, 0);
    }
    __syncthreads();
    cur ^= 1;
  }
}

// ---- QKV projection GEMM (scale folds 1/sqrt(dk)*log2(e) into Q) ------------
__global__ __launch_bounds__(256) void gemm_qkv_kernel(
    const unsigned short* __restrict__ Ain, const unsigned short* __restrict__ Bin,
    const float* __restrict__ bias, unsigned short* __restrict__ Out, float scale) {
  __shared__ __align__(16) unsigned short lA[2][128 * 64];
  __shared__ __align__(16) unsigned short lB[2][128 * 64];
  int m0 = blockIdx.x * 128, n0 = blockIdx.y * 128;
  const unsigned short* A = Ain + (size_t)m0 * HID;
  const unsigned short* B = Bin + (size_t)n0 * HID;
  f32x4_t acc[4][4] = {};
  int tid = threadIdx.x;
  gemm_tile_mainloop(A, B, lA, lB, tid, acc);
  int lane = tid & 63, w = tid >> 6;
  int wr = (w >> 1) << 6, wc = (w & 1) << 6;
#pragma unroll
  for (int mi = 0; mi < 4; ++mi)
#pragma unroll
    for (int ni = 0; ni < 4; ++ni) {
      int col = n0 + wc + ni * 16 + (lane & 15);
      float bb = bias[col];
      int h = col >> 6, d = col & 63;
#pragma unroll
      for (int r = 0; r < 4; ++r) {
        int row = m0 + wr + mi * 16 + ((lane >> 4) << 2) + r;
        int b = row >> 11, s = row & 2047;
        Out[((((size_t)b * NH + h) * SLEN + s) << 6) + d] = bfbits((acc[mi][ni][r] + bb) * scale);
      }
    }
}

// ---- output projection GEMM: fp32 out, row-major ----------------------------
__global__ __launch_bounds__(256) void gemm_out_kernel(
    const unsigned short* __restrict__ Ob, const unsigned short* __restrict__ WoT,
    const float* __restrict__ bo, float* __restrict__ out) {
  __shared__ __align__(16) unsigned short lA[2][128 * 64];
  __shared__ __align__(16) unsigned short lB[2][128 * 64];
  int m0 = blockIdx.x * 128, n0 = blockIdx.y * 128;
  const unsigned short* A = Ob + (size_t)m0 * HID;
  const unsigned short* B = WoT + (size_t)n0 * HID;
  f32x4_t acc[4][4] = {};
  int tid = threadIdx.x;
  gemm_tile_mainloop(A, B, lA, lB, tid, acc);
  int lane = tid & 63, w = tid >> 6;
  int wr = (w >> 1) << 6, wc = (w & 1) << 6;
#pragma unroll
  for (int mi = 0; mi < 4; ++mi)
#pragma unroll
    for (int ni = 0; ni < 4; ++ni) {
      int col = n0 + wc + ni * 16 + (lane & 15);
      float bb = bo[col];
#pragma unroll
      for (int r = 0; r < 4; ++r) {
        int row = m0 + wr + mi * 16 + ((lane >> 4) << 2) + r;
        out[(size_t)row * HID + col] = acc[mi][ni][r] + bb;
      }
    }
}

// ---- flash attention on 32x32x16 MFMAs --------------------------------------
// S^T = mfma32(K, Q): q = lane&31, kv = (reg&3)+8*(reg>>2)+4*(lane>>5)+32*kvb
// PV:  O^T = mfma32(V^T, P^T): P^T B-frag built by 2 permlane32_swap per step.
__global__ __launch_bounds__(256) void attn_kernel(
    const unsigned short* __restrict__ Q, const unsigned short* __restrict__ K,
    const unsigned short* __restrict__ VT, const unsigned long long* __restrict__ mbits,
    unsigned short* __restrict__ O) {
  __shared__ __align__(16) unsigned short lK[2][64 * 64];  // [kv][d]  swizzled
  __shared__ __align__(16) unsigned short lV[2][64 * 64];  // [dv][kv] swizzled
  int tid = threadIdx.x, lane = tid & 63, w = tid >> 6;
  int h32 = lane >> 5, l31 = lane & 31;
  int bid = blockIdx.x;
  int bh = (bid & 7) * 8 + ((bid >> 3) >> 4);
  int qt = (bid >> 3) & 15;
  int b = bh >> 4, h = bh & 15;
  int q0 = qt * 128;
  int q = q0 + w * 32 + l31;   // this lane's q row
  const unsigned short* Qb = Q + (size_t)bh * (SLEN * 64);

  // hoisted staging source pointers (per thread), bumped by constants per tile
  int f0 = tid, f1 = 256 + tid;
  int r0 = f0 >> 3, r1 = f1 >> 3;
  int s0 = (f0 & 7) ^ (r0 & 7), s1 = (f1 & 7) ^ (r1 & 7);
  const unsigned short* kS0 = K + (size_t)bh * (SLEN * 64) + (size_t)r0 * 64 + s0 * 8;
  const unsigned short* kS1 = K + (size_t)bh * (SLEN * 64) + (size_t)r1 * 64 + s1 * 8;
  const unsigned short* vS0 = VT + (size_t)bh * (64 * SLEN) + (size_t)r0 * SLEN + s0 * 8;
  const unsigned short* vS1 = VT + (size_t)bh * (64 * SLEN) + (size_t)r1 * SLEN + s1 * 8;
  int d0off = (0 * 256 + w * 64) << 3;
  int d1off = (1 * 256 + w * 64) << 3;
  // hoisted mask row pointer (one q per lane)
  const unsigned long long* mp = mbits + ((size_t)b * SLEN + q) * 32;

  // Q fragments: B-operand of 32x32x16, k = ks*16 + h32*8 + e
  bf16x8_t qf[4];
#pragma unroll
  for (int ks = 0; ks < 4; ++ks)
    qf[ks] = *(const bf16x8_t*)(Qb + (size_t)q * 64 + ks * 16 + h32 * 8);

  f32x16_t aco[2] = {};   // O^T per dv-block: dv=(reg&3)+8*(reg>>2)+4*h32+32*dvb
  float lsum = 0.f;

  // ---- prologue: stage tile 0 ----
  gload_lds16(kS0, (unsigned short*)lK[0] + d0off);
  gload_lds16(kS1, (unsigned short*)lK[0] + d1off);
  gload_lds16(vS0, (unsigned short*)lV[0] + d0off);
  gload_lds16(vS1, (unsigned short*)lV[0] + d1off);
  kS0 += 4096; kS1 += 4096; vS0 += 64; vS1 += 64;
  __syncthreads();

  int cur = 0;
  for (int kt = 0; kt < SLEN / 64; ++kt) {
    // ---- issue next-tile staging (hides under this tile's compute) ----
    if (kt + 1 < SLEN / 64) {
      unsigned short* kn = (unsigned short*)lK[cur ^ 1];
      unsigned short* vn = (unsigned short*)lV[cur ^ 1];
      gload_lds16(kS0, kn + d0off);
      gload_lds16(kS1, kn + d1off);
      gload_lds16(vS0, vn + d0off);
      gload_lds16(vS1, vn + d1off);
      kS0 += 4096; kS1 += 4096; vS0 += 64; vS1 += 64;
    }

    // ---- mask bits early ----
    unsigned long long bg = mp[kt];
    unsigned int mwl = (unsigned int)(bg >> (4 * h32));
    unsigned int mwh = (unsigned int)(bg >> (32 + 4 * h32));

    const unsigned short* kbuf = lK[cur];
    const unsigned short* vbuf = lV[cur];

    // ---- QK^T: st[kvb] = S^T_log2[kv block][q=l31] ----
    f32x16_t st[2] = {};
    __builtin_amdgcn_s_setprio(1);
#pragma unroll
    for (int kvb = 0; kvb < 2; ++kvb) {
#pragma unroll
      for (int ks = 0; ks < 4; ++ks) {
        int row = kvb * 32 + l31;
        int slot = (2 * ks + h32) ^ (row & 7);
        bf16x8_t kf = *(const bf16x8_t*)(kbuf + (row << 6) + (slot << 3));
        st[kvb] = __builtin_amdgcn_mfma_f32_32x32x16_bf16(kf, qf[ks], st[kvb], 0, 0, 0);
      }
    }
    __builtin_amdgcn_s_setprio(0);

    // ---- static-max softmax: p = mask ? 2^st : 0 (all in-lane) ----
    float p[32];
#pragma unroll
    for (int kvb = 0; kvb < 2; ++kvb) {
      unsigned int mw = kvb ? mwh : mwl;
#pragma unroll
      for (int i = 0; i < 16; ++i) {
        float e = fast_exp2(st[kvb][i]);
        int pos = (i & 3) + 8 * (i >> 2);
        p[kvb * 16 + i] = ((mw >> pos) & 1u) ? e : 0.f;
      }
    }
    // l partial: in-lane tree + half-exchange
    float t8[8];
#pragma unroll
    for (int i = 0; i < 8; ++i)
      t8[i] = (p[4 * i] + p[4 * i + 1]) + (p[4 * i + 2] + p[4 * i + 3]);
    float sml = ((t8[0] + t8[1]) + (t8[2] + t8[3])) + ((t8[4] + t8[5]) + (t8[6] + t8[7]));
    lsum += sml + __shfl_xor(sml, 32, 64);
    // pack P^T to bf16 pairs
    unsigned int pw[16];
#pragma unroll
    for (int j = 0; j < 16; ++j) pw[j] = packbf(p[2 * j], p[2 * j + 1]);

    // ---- PV: per kv-step build B-frag via 2 permlane32_swap, 2 MFMAs ----
    __builtin_amdgcn_s_setprio(1);
#pragma unroll
    for (int s4 = 0; s4 < 4; ++s4) {
      unsigned int c0 = pw[4 * s4 + 0], c1 = pw[4 * s4 + 1];
      unsigned int c2 = pw[4 * s4 + 2], c3 = pw[4 * s4 + 3];
      asm("v_permlane32_swap_b32 %0, %1" : "+v"(c0), "+v"(c2));
      asm("v_permlane32_swap_b32 %0, %1" : "+v"(c1), "+v"(c3));
      union { unsigned int u[4]; bf16x8_t v; } pf;
      pf.u[0] = c0; pf.u[1] = c1; pf.u[2] = c2; pf.u[3] = c3;
#pragma unroll
      for (int dvb = 0; dvb < 2; ++dvb) {
        int row = dvb * 32 + l31;
        int slot = (2 * s4 + h32) ^ (row & 7);
        bf16x8_t vf = *(const bf16x8_t*)(vbuf + (row << 6) + (slot << 3));
        aco[dvb] = __builtin_amdgcn_mfma_f32_32x32x16_bf16(vf, pf.v, aco[dvb], 0, 0, 0);
      }
    }
    __builtin_amdgcn_s_setprio(0);

    __syncthreads();  // drains vmcnt (K/V prefetch); releases buffers
    cur ^= 1;
  }

  // ---- epilogue: normalize O^T, transpose through lK scratch ----
  unsigned short* eb = (unsigned short*)lK;  // 16KB, rows [128][64 dv]
  float inv = 1.0f / lsum;
  int row = w * 32 + l31;
#pragma unroll
  for (int dvb = 0; dvb < 2; ++dvb)
#pragma unroll
    for (int i = 0; i < 4; ++i)
#pragma unroll
      for (int jj = 0; jj < 2; ++jj) {
        float a0 = aco[dvb][4 * i + 2 * jj] * inv;
        float a1 = aco[dvb][4 * i + 2 * jj + 1] * inv;
        unsigned int v = packbf(a0, a1);
        int dv0 = 32 * dvb + 8 * i + 4 * h32 + 2 * jj;
        int slot = (dv0 >> 3) ^ (row & 7);
        *(unsigned int*)((char*)eb + row * 128 + slot * 16 + (dv0 & 7) * 2) = v;
      }
  int g = lane >> 4, ql = lane & 15;
#pragma unroll
  for (int it = 0; it < 8; ++it) {
    int rloc = g + 4 * it;
    int rrow = w * 32 + rloc;
    int sl = (ql >> 1) ^ (rrow & 7);
    uint2 v = *(const uint2*)((const char*)eb + rrow * 128 + sl * 16 + (ql & 1) * 8);
    int qrow = q0 + rrow;
    *(uint2*)(O + (((size_t)b * SLEN + qrow) << 10) + h * 64 + ql * 4) = v;
  }
}

// ---------------------------------------------------------------------------
extern "C" void kernel_launch(void* const* d_in, const int* in_sizes, int n_in,
                              void* d_out, int out_size, void* d_ws, size_t ws_size,
                              hipStream_t stream) {
  (void)in_sizes; (void)n_in; (void)out_size; (void)ws_size;
  const float* xq = (const float*)d_in[0];
  const float* xk = (const float*)d_in[1];
  const float* xv = (const float*)d_in[2];
  const void*  mask = d_in[3];
  const float* wq = (const float*)d_in[4];
  const float* bq = (const float*)d_in[5];
  const float* wk = (const float*)d_in[6];
  const float* bk = (const float*)d_in[7];
  const float* wv = (const float*)d_in[8];
  const float* bv = (const float*)d_in[9];
  const float* wo = (const float*)d_in[10];
  const float* bo = (const float*)d_in[11];
  float* out = (float*)d_out;

  char* ws = (char*)d_ws;
  unsigned short* XbZ  = (unsigned short*)(ws);                   // 16 MiB per-z bf16 X
  unsigned short* Ob   = (unsigned short*)(ws);                   // overlays XbZ
  unsigned short* Wt   = (unsigned short*)(ws + 16777216ull);     // 8 MiB packed weights
  unsigned short* QKV  = (unsigned short*)(ws + 25165824ull);     // 48 MiB
  unsigned int*   flag = (unsigned int*)(ws + 75497472ull);       // 4 B
  // d_out overlay: bitmask [0,2MiB), VT [2,18MiB). gemm_out overwrites last.
  unsigned long long* mbits = (unsigned long long*)d_out;
  unsigned short* VTp = (unsigned short*)((char*)d_out + 2097152ull);

  const float* xs[3]   = {xq, xk, xv};
  const float* bias[3] = {bq, bk, bv};

  detect_mask_kernel<<<1, 256, 0, stream>>>((const unsigned int*)mask, flag);
  mask_bits_kernel<<<4096, 256, 0, stream>>>(mask, flag, mbits);
  pack_w_kernel<<<dim3(1024, 4), 256, 0, stream>>>(wq, wk, wv, wo, Wt);
  for (int z = 0; z < 3; ++z) {
    cvt_x_kernel<<<8192, 256, 0, stream>>>(xs[z], XbZ);
    gemm_qkv_kernel<<<dim3(64, 8), 256, 0, stream>>>(
        XbZ, Wt + (size_t)z * (HID * HID), bias[z],
        QKV + (size_t)z * ((size_t)MROWS * 1024), z == 0 ? 0.125f * L2E : 1.0f);
  }
  transpose_v_kernel<<<dim3(32, 64), 256, 0, stream>>>(QKV + 16777216ull, VTp);
  attn_kernel<<<1024, 256, 0, stream>>>(QKV, QKV + 8388608ull, VTp, mbits, Ob);
  gemm_out_kernel<<<dim3(64, 8), 256, 0, stream>>>(Ob, Wt + 3ull * (HID * HID), bo, out);
}